// Round 6
// baseline (835.229 us; speedup 1.0000x reference)
//
#include <hip/hip_runtime.h>

#define NN 300000
#define FF 64
#define EE 2400000
#define FEA 8
#define RAWCAP 131072   // >= 8*129*97 = 100104 guaranteed by IMG_W/H bounds
#define LCAP 2048       // big-bucket bitonic capacity (block path)

typedef unsigned long long ull;

__device__ __forceinline__ unsigned fenc(float f) {
  unsigned b = __float_as_uint(f);
  return (b & 0x80000000u) ? ~b : (b | 0x80000000u);
}
__device__ __forceinline__ float fdec(unsigned e) {
  unsigned b = (e & 0x80000000u) ? (e ^ 0x80000000u) : ~e;
  return __uint_as_float(b);
}

__global__ void init_hdr_k(unsigned* hdr) {
  if (threadIdx.x == 0) {
    hdr[0] = 0xFFFFFFFFu; hdr[1] = 0xFFFFFFFFu;  // min enc
    hdr[2] = 0u;          hdr[3] = 0u;           // max enc
    hdr[9] = 0u;          hdr[10] = 0u;          // compact-list counters
  }
}

// 128 blocks; LDS block-reduce, 4 atomics per block
__global__ void minmax_k(const float* __restrict__ pos, unsigned* hdr) {
  __shared__ unsigned red[4][4];
  int t = blockIdx.x * blockDim.x + threadIdx.x;
  float mnx = 1e30f, mny = 1e30f, mxx = -1e30f, mxy = -1e30f;
  for (int i = t; i < NN; i += gridDim.x * blockDim.x) {
    float px = pos[i * 3 + 1], py = pos[i * 3 + 2];
    mnx = fminf(mnx, px); mny = fminf(mny, py);
    mxx = fmaxf(mxx, px); mxy = fmaxf(mxy, py);
  }
  for (int o = 1; o < 64; o <<= 1) {
    mnx = fminf(mnx, __shfl_xor(mnx, o));
    mny = fminf(mny, __shfl_xor(mny, o));
    mxx = fmaxf(mxx, __shfl_xor(mxx, o));
    mxy = fmaxf(mxy, __shfl_xor(mxy, o));
  }
  int wid = threadIdx.x >> 6;
  if ((threadIdx.x & 63) == 0) {
    red[wid][0] = fenc(mnx); red[wid][1] = fenc(mny);
    red[wid][2] = fenc(mxx); red[wid][3] = fenc(mxy);
  }
  __syncthreads();
  if (threadIdx.x == 0) {
    unsigned a0 = red[0][0], a1 = red[0][1], a2 = red[0][2], a3 = red[0][3];
    for (int k = 1; k < 4; k++) {
      a0 = min(a0, red[k][0]); a1 = min(a1, red[k][1]);
      a2 = max(a2, red[k][2]); a3 = max(a3, red[k][3]);
    }
    atomicMin(&hdr[0], a0); atomicMin(&hdr[1], a1);
    atomicMax(&hdr[2], a2); atomicMax(&hdr[3], a3);
  }
}

__global__ void dims_k(unsigned* hdr) {
  if (threadIdx.x == 0 && blockIdx.x == 0) {
    float mnx = fdec(hdr[0]), mny = fdec(hdr[1]);
    float mxx = fdec(hdr[2]), mxy = fdec(hdr[3]);
    int d0 = (int)(floorf((mxx - mnx) / 5.0f) + 1.0f);
    int d1 = (int)(floorf((mxy - mny) / 5.0f) + 1.0f);
    hdr[4] = (unsigned)d0;
    hdr[5] = (unsigned)d1;
    ((float*)hdr)[6] = mnx;
    ((float*)hdr)[7] = mny;
  }
}

__global__ void raw_k(const float* __restrict__ pos, const int* __restrict__ batch,
                      const unsigned* __restrict__ hdr, int* __restrict__ cluster,
                      unsigned* __restrict__ flags) {
  int i = blockIdx.x * blockDim.x + threadIdx.x;
  if (i >= NN) return;
  float mnx = ((const float*)hdr)[6], mny = ((const float*)hdr)[7];
  int d0 = (int)hdr[4], d1 = (int)hdr[5];
  int c0 = (int)floorf((pos[i * 3 + 1] - mnx) / 5.0f);
  int c1 = (int)floorf((pos[i * 3 + 2] - mny) / 5.0f);
  int raw = batch[i] * (d0 * d1) + c0 * d1 + c1;
  cluster[i] = raw;
  flags[raw] = 1u;
}

// generic exclusive-scan pieces (1024 elems per block)
__global__ void scan_part(const unsigned* __restrict__ in, unsigned* __restrict__ out,
                          unsigned* __restrict__ bsum, int ntot, unsigned* __restrict__ total_out) {
  __shared__ unsigned sc[256];
  int base = blockIdx.x * 1024 + threadIdx.x * 4;
  unsigned v[4]; unsigned s = 0;
#pragma unroll
  for (int k = 0; k < 4; k++) {
    int i = base + k;
    v[k] = (i < ntot) ? in[i] : 0u;
    s += v[k];
  }
  sc[threadIdx.x] = s;
  __syncthreads();
  unsigned xv = s;
  for (int o = 1; o < 256; o <<= 1) {
    unsigned y = (threadIdx.x >= o) ? sc[threadIdx.x - o] : 0u;
    __syncthreads();
    xv += y;
    sc[threadIdx.x] = xv;
    __syncthreads();
  }
  unsigned run = xv - s;
#pragma unroll
  for (int k = 0; k < 4; k++) {
    int i = base + k;
    if (i < ntot) out[i] = run;
    run += v[k];
  }
  if (threadIdx.x == 255) {
    if (bsum) bsum[blockIdx.x] = xv;
    if (total_out && blockIdx.x == 0) *total_out = xv;
  }
}

__global__ void scan_add(unsigned* __restrict__ out, const unsigned* __restrict__ bsum, int ntot) {
  unsigned add = bsum[blockIdx.x];
  int base = blockIdx.x * 1024;
  for (int k = threadIdx.x; k < 1024; k += 256) {
    int i = base + k;
    if (i < ntot) out[i] += add;
  }
}

// map raw->cluster id and count members per cluster
__global__ void node_cnt_k(const unsigned* __restrict__ rank, int* __restrict__ cluster,
                           unsigned* __restrict__ cnt) {
  int i = blockIdx.x * blockDim.x + threadIdx.x;
  if (i >= NN) return;
  int cl = (int)rank[cluster[i]];
  cluster[i] = cl;
  atomicAdd(&cnt[cl], 1u);
}

__global__ void node_scatter_k(const int* __restrict__ cluster,
                               const unsigned* __restrict__ node_off,
                               unsigned* __restrict__ node_fill,
                               int* __restrict__ nlist) {
  int i = blockIdx.x * blockDim.x + threadIdx.x;
  if (i >= NN) return;
  int cl = cluster[i];
  unsigned p = node_off[cl] + atomicAdd(&node_fill[cl], 1u);
  nlist[p] = i;
}

// one wave per cluster: gather member rows, fmax in registers, write once.
__global__ void __launch_bounds__(256)
cluster_reduce_k(const float* __restrict__ x, const float* __restrict__ pos,
                 const int* __restrict__ batch, const int* __restrict__ nlist,
                 const unsigned* __restrict__ node_off, const unsigned* __restrict__ hdr,
                 float* __restrict__ out_x, float* __restrict__ out_pos,
                 float* __restrict__ out_batch) {
  int w = (blockIdx.x * blockDim.x + threadIdx.x) >> 6;
  int nw = (gridDim.x * blockDim.x) >> 6;
  int f = threadIdx.x & 63;
  int ncl = (int)hdr[8];
  for (int c = w; c < ncl; c += nw) {
    unsigned o0 = node_off[c];
    int len = (int)(node_off[c + 1] - o0);
    float mx = -1e38f;
    long long ps = 0;
    for (int m = 0; m < len; m++) {
      int nd = nlist[o0 + m];
      mx = fmaxf(mx, x[(size_t)nd * FF + f]);
      if (f < 3) ps += (long long)llrintf(pos[nd * 3 + f] * 65536.0f);
    }
    out_x[(size_t)c * FF + f] = mx;
    if (f < 3) {
      float v = (float)((double)ps / 65536.0 / (double)len);
      if (f > 0) v = floorf(v / 4.0f);
      out_pos[c * 3 + f] = v;
    }
    if (f == 63) out_batch[c] = (float)batch[nlist[o0]];
  }
}

// rows >= ncl: zeros for x/pos, -1 for batch (exact-range grid-stride)
__global__ void node_tail_k(const unsigned* __restrict__ hdr,
                            float* __restrict__ out_x, float* __restrict__ out_pos,
                            float* __restrict__ out_batch) {
  int ncl = (int)hdr[8];
  int total = (NN - ncl) * FF;
  for (int i = blockIdx.x * blockDim.x + threadIdx.x; i < total;
       i += gridDim.x * blockDim.x) {
    int r = ncl + (i >> 6), f = i & 63;
    out_x[(size_t)r * FF + f] = 0.0f;
    if (f < 3) out_pos[r * 3 + f] = 0.0f;
    if (f == 0) out_batch[r] = -1.0f;
  }
}

__global__ void edge_cnt_k(const int* __restrict__ ei, const int* __restrict__ cluster,
                           unsigned* __restrict__ cs_cnt) {
  int t = blockIdx.x * blockDim.x + threadIdx.x;
  if (t >= EE) return;
  int s = cluster[ei[t]];
  int d = cluster[ei[EE + t]];
  if (s == d) s = NN;
  atomicAdd(&cs_cnt[s], 1u);
}

// XCD-sliced scatter: 8 block-groups; group g streams ALL edges (nt loads)
// but scatters only edges whose bucket start cs_off[b] lies in keys-slice g
// (~2.4MB, XCD-L2-resident -> key lines fill up before write-back).
__global__ void __launch_bounds__(256)
edge_scatter_k(const int* __restrict__ ei, const int* __restrict__ cluster,
               const unsigned* __restrict__ cs_off, unsigned* __restrict__ cs_fill,
               ull* __restrict__ keys) {
  int g = blockIdx.x & 7;
  int j = blockIdx.x >> 3;
  int stride = (gridDim.x >> 3) * blockDim.x;
  for (int t = j * blockDim.x + threadIdx.x; t < EE; t += stride) {
    int src = __builtin_nontemporal_load(&ei[t]);
    int b = cluster[src];
    unsigned off = cs_off[b];
    if ((int)(off / 300000u) != g) continue;
    int d = cluster[__builtin_nontemporal_load(&ei[EE + t])];
    if (b == d) continue;   // self-loop: never emitted, drop
    unsigned p = off + atomicAdd(&cs_fill[b], 1u);
    keys[p] = ((ull)(unsigned)d << 22) | (unsigned)t;
  }
}

// split non-empty buckets into small (len<=64, wave path) and big (block path);
// wave-aggregated atomics (1/wave, not 1/thread)
__global__ void compact_k(const unsigned* __restrict__ cs_off, unsigned* hdr,
                          int* __restrict__ nb_small, int* __restrict__ nb_big) {
  int b = blockIdx.x * blockDim.x + threadIdx.x;
  int lane = threadIdx.x & 63;
  int len = 0;
  if (b < NN) len = (int)(cs_off[b + 1] - cs_off[b]);
  bool sm = (len > 0) && (len <= 64);
  bool bg = len > 64;
  ull msm = __ballot(sm);
  ull mbg = __ballot(bg);
  unsigned bs = 0, bb = 0;
  if (lane == 0) {
    if (msm) bs = atomicAdd(&hdr[9], (unsigned)__popcll(msm));
    if (mbg) bb = atomicAdd(&hdr[10], (unsigned)__popcll(mbg));
  }
  bs = (unsigned)__shfl((int)bs, 0);
  bb = (unsigned)__shfl((int)bb, 0);
  ull lt = (1ULL << lane) - 1ULL;
  if (sm) nb_small[bs + (unsigned)__popcll(msm & lt)] = b;
  if (bg) nb_big[bb + (unsigned)__popcll(mbg & lt)] = b;
}

// one wave per bucket, no sort: count distinct cd via readlane head-detection
__global__ void __launch_bounds__(256)
group_small_k(const ull* __restrict__ keys, const unsigned* __restrict__ cs_off,
              const int* __restrict__ nb_small, const unsigned* __restrict__ hdr,
              unsigned* __restrict__ grp_cnt) {
  int w = (blockIdx.x * blockDim.x + threadIdx.x) >> 6;
  int nw = (gridDim.x * blockDim.x) >> 6;
  int lane = threadIdx.x & 63;
  int cnt = (int)hdr[9];
  for (int bi = w; bi < cnt; bi += nw) {
    int b = nb_small[bi];
    unsigned o0 = cs_off[b];
    int len = (int)(cs_off[b + 1] - o0);
    unsigned cdv = 0xFFFFFFFFu;
    if (lane < len) cdv = (unsigned)(__builtin_nontemporal_load(&keys[o0 + lane]) >> 22);
    bool head = (lane < len);
    for (int j = 0; j < len; ++j) {
      unsigned cj = (unsigned)__builtin_amdgcn_readlane((int)cdv, j);
      if (cj == cdv && j < lane) head = false;
    }
    ull M = __ballot(head);
    if (lane == 0) grp_cnt[b] = (unsigned)__popcll(M);
  }
}

// one wave per bucket: hoisted own-ea load hides gather latency under the
// head/rank readlane loops; dup-group members merged via register shfl
// (no second global gather).
__global__ void __launch_bounds__(256)
emit_small_k(const ull* __restrict__ keys, const unsigned* __restrict__ cs_off,
             const int* __restrict__ nb_small, const unsigned* __restrict__ hdr,
             const unsigned* __restrict__ grp_base, const float* __restrict__ ea,
             float* __restrict__ out_src, float* __restrict__ out_dst,
             float* __restrict__ out_ea) {
  int w = (blockIdx.x * blockDim.x + threadIdx.x) >> 6;
  int nw = (gridDim.x * blockDim.x) >> 6;
  int lane = threadIdx.x & 63;
  int cnt = (int)hdr[9];
  for (int bi = w; bi < cnt; bi += nw) {
    int b = nb_small[bi];
    unsigned o0 = cs_off[b];
    int len = (int)(cs_off[b + 1] - o0);
    unsigned cdv = 0xFFFFFFFFu, eidv = 0u;
    if (lane < len) {
      ull key = __builtin_nontemporal_load(&keys[o0 + lane]);
      cdv = (unsigned)(key >> 22);
      eidv = (unsigned)(key & 0x3FFFFFULL);
    }
    float4 v0 = make_float4(0.f, 0.f, 0.f, 0.f), v1 = v0;
    if (lane < len) {
      const float4* p = (const float4*)&ea[(size_t)eidv * FEA];
      v0 = p[0]; v1 = p[1];
    }
    bool head = (lane < len);
    for (int j = 0; j < len; ++j) {
      unsigned cj = (unsigned)__builtin_amdgcn_readlane((int)cdv, j);
      if (cj == cdv && j < lane) head = false;
    }
    ull M = __ballot(head);
    bool allsingle = ((int)__popcll(M) == len);
    unsigned r = 0;
    for (int j = 0; j < len; ++j) {
      unsigned cj = (unsigned)__builtin_amdgcn_readlane((int)cdv, j);
      if (((M >> j) & 1ULL) && cj < cdv) r++;
    }
    float4 a0 = v0, a1 = v1;
    if (!allsingle) {
      for (int j = 0; j < len; ++j) {
        unsigned cj = (unsigned)__builtin_amdgcn_readlane((int)cdv, j);
        bool take = (cj == cdv) && (j != lane);
        float t0 = __shfl(v0.x, j), t1 = __shfl(v0.y, j);
        float t2 = __shfl(v0.z, j), t3 = __shfl(v0.w, j);
        float t4 = __shfl(v1.x, j), t5 = __shfl(v1.y, j);
        float t6 = __shfl(v1.z, j), t7 = __shfl(v1.w, j);
        if (take) {
          a0.x += t0; a0.y += t1; a0.z += t2; a0.w += t3;
          a1.x += t4; a1.y += t5; a1.z += t6; a1.w += t7;
        }
      }
    }
    if (head) {
      unsigned row = grp_base[b] + r;
      out_src[row] = (float)b;
      out_dst[row] = (float)cdv;
      float4* o = (float4*)&out_ea[(size_t)row * FEA];
      o[0] = a0; o[1] = a1;
    }
  }
}

__global__ void __launch_bounds__(256)
sort_big_k(ull* __restrict__ keys, const unsigned* __restrict__ cs_off,
           const int* __restrict__ nb_big, const unsigned* __restrict__ hdr,
           unsigned* __restrict__ grp_cnt) {
  __shared__ ull sm[LCAP];
  __shared__ ull rb[256];
  __shared__ int ri[256];
  __shared__ unsigned s4[4];
  int nbig = (int)hdr[10];
  for (int bi = blockIdx.x; bi < nbig; bi += gridDim.x) {
    int b = nb_big[bi];
    unsigned o0 = cs_off[b];
    int len = (int)(cs_off[b + 1] - o0);
    if (len <= LCAP) {
      int np = 1; while (np < len) np <<= 1;
      for (int i = threadIdx.x; i < np; i += 256)
        sm[i] = (i < len) ? keys[o0 + i] : ~0ULL;
      __syncthreads();
      for (int k = 2; k <= np; k <<= 1) {
        for (int j = k >> 1; j > 0; j >>= 1) {
          for (int i = threadIdx.x; i < np; i += 256) {
            int ixj = i ^ j;
            if (ixj > i) {
              ull a = sm[i], c = sm[ixj];
              bool up = ((i & k) == 0);
              if (up ? (a > c) : (a < c)) { sm[i] = c; sm[ixj] = a; }
            }
          }
          __syncthreads();
        }
      }
      unsigned g = 0;
      for (int i = threadIdx.x; i < len; i += 256) {
        ull kk = sm[i];
        keys[o0 + i] = kk;
        unsigned cd = (unsigned)(kk >> 22);
        if (i == 0 || (unsigned)(sm[i - 1] >> 22) != cd) g++;
      }
      for (int o = 32; o > 0; o >>= 1) g += __shfl_down(g, o);
      if ((threadIdx.x & 63) == 0) s4[threadIdx.x >> 6] = g;
      __syncthreads();
      if (threadIdx.x == 0) grp_cnt[b] = s4[0] + s4[1] + s4[2] + s4[3];
      __syncthreads();
    } else {
      for (int p = 0; p < len - 1; p++) {
        ull best = ~0ULL; int bidx = -1;
        for (int i = p + threadIdx.x; i < len; i += 256) {
          ull v = keys[o0 + i];
          if (v < best) { best = v; bidx = i; }
        }
        rb[threadIdx.x] = best; ri[threadIdx.x] = bidx;
        __syncthreads();
        for (int sd = 128; sd > 0; sd >>= 1) {
          if (threadIdx.x < sd && rb[threadIdx.x + sd] < rb[threadIdx.x]) {
            rb[threadIdx.x] = rb[threadIdx.x + sd]; ri[threadIdx.x] = ri[threadIdx.x + sd];
          }
          __syncthreads();
        }
        if (threadIdx.x == 0) {
          int m = ri[0];
          ull tmp = keys[o0 + p];
          keys[o0 + p] = rb[0];
          keys[o0 + m] = tmp;
        }
        __syncthreads();
      }
      unsigned g = 0;
      for (int i = threadIdx.x; i < len; i += 256) {
        unsigned cd = (unsigned)(keys[o0 + i] >> 22);
        if (i == 0 || (unsigned)(keys[o0 + i - 1] >> 22) != cd) g++;
      }
      for (int o = 32; o > 0; o >>= 1) g += __shfl_down(g, o);
      if ((threadIdx.x & 63) == 0) s4[threadIdx.x >> 6] = g;
      __syncthreads();
      if (threadIdx.x == 0) grp_cnt[b] = s4[0] + s4[1] + s4[2] + s4[3];
      __syncthreads();
    }
  }
}

__global__ void __launch_bounds__(256)
emit_big_k(const ull* __restrict__ keys, const unsigned* __restrict__ cs_off,
           const int* __restrict__ nb_big, const unsigned* __restrict__ hdr,
           const unsigned* __restrict__ grp_base, const float* __restrict__ ea,
           float* __restrict__ out_src, float* __restrict__ out_dst,
           float* __restrict__ out_ea) {
  __shared__ unsigned sc[256];
  __shared__ unsigned s_carry;
  int nbig = (int)hdr[10];
  for (int bi = blockIdx.x; bi < nbig; bi += gridDim.x) {
    int b = nb_big[bi];
    unsigned o0 = cs_off[b];
    int len = (int)(cs_off[b + 1] - o0);
    unsigned base = grp_base[b];
    if (threadIdx.x == 0) s_carry = 0;
    __syncthreads();
    for (int c0 = 0; c0 < len; c0 += 256) {
      int i = c0 + threadIdx.x;
      unsigned cd = 0; bool newg = false;
      if (i < len) {
        ull kk = keys[o0 + i];
        cd = (unsigned)(kk >> 22);
        newg = (i == 0) || ((unsigned)(keys[o0 + i - 1] >> 22) != cd);
      }
      unsigned flag = newg ? 1u : 0u;
      sc[threadIdx.x] = flag;
      __syncthreads();
      unsigned xv = flag;
      for (int o = 1; o < 256; o <<= 1) {
        unsigned y = (threadIdx.x >= o) ? sc[threadIdx.x - o] : 0u;
        __syncthreads();
        xv += y;
        sc[threadIdx.x] = xv;
        __syncthreads();
      }
      unsigned carry_old = s_carry;
      if (newg) {
        float a0=0,a1=0,a2=0,a3=0,a4=0,a5=0,a6=0,a7=0;
        int j = i;
        while (j < len) {
          ull k2 = keys[o0 + j];
          if ((unsigned)(k2 >> 22) != cd) break;
          unsigned eid = (unsigned)(k2 & 0x3FFFFFULL);
          const float* p = &ea[(size_t)eid * FEA];
          a0+=p[0];a1+=p[1];a2+=p[2];a3+=p[3];a4+=p[4];a5+=p[5];a6+=p[6];a7+=p[7];
          j++;
        }
        unsigned row = base + carry_old + xv - 1u;
        out_src[row] = (float)b;
        out_dst[row] = (float)cd;
        float* q = &out_ea[(size_t)row * FEA];
        q[0]=a0;q[1]=a1;q[2]=a2;q[3]=a3;q[4]=a4;q[5]=a5;q[6]=a6;q[7]=a7;
      }
      __syncthreads();
      if (threadIdx.x == 255) s_carry = carry_old + xv;
      __syncthreads();
    }
  }
}

// rows >= T (total groups) get -1/-1 and zero ea (exact-range grid-stride)
__global__ void tail_fill_k(const unsigned* __restrict__ grp_base,
                            float* __restrict__ out_src, float* __restrict__ out_dst,
                            float* __restrict__ out_ea) {
  int T = (int)grp_base[NN];
  for (int t = T + blockIdx.x * blockDim.x + threadIdx.x; t < EE;
       t += gridDim.x * blockDim.x) {
    out_src[t] = -1.0f;
    out_dst[t] = -1.0f;
    float4 z = make_float4(0.f, 0.f, 0.f, 0.f);
    float4* o = (float4*)&out_ea[(size_t)t * FEA];
    o[0] = z; o[1] = z;
  }
}

extern "C" void kernel_launch(void* const* d_in, const int* in_sizes, int n_in,
                              void* d_out, int out_size, void* d_ws, size_t ws_size,
                              hipStream_t stream) {
  const float* x   = (const float*)d_in[0];
  const float* pos = (const float*)d_in[1];
  const int* batch = (const int*)d_in[2];
  const int* ei    = (const int*)d_in[3];
  const float* ea  = (const float*)d_in[4];
  float* out = (float*)d_out;

  const size_t OX = 0;
  const size_t OP = (size_t)NN * FF;
  const size_t OB = OP + (size_t)NN * 3;
  const size_t OE = OB + (size_t)NN;
  const size_t OA = OE + (size_t)2 * EE;

  char* w = (char*)d_ws;
  size_t woff = 0;
  auto alloc = [&](size_t bytes) -> void* {
    void* p = w + woff;
    woff += (bytes + 255) & ~(size_t)255;
    return p;
  };
  // zeroed region (one memset)
  unsigned* rank    = (unsigned*)alloc((size_t)RAWCAP * 4);     // reuse: nb_big
  unsigned* cnt     = (unsigned*)alloc((size_t)(NN + 1) * 4);   // reuse: nb_small
  unsigned* node_fill = (unsigned*)alloc((size_t)NN * 4);
  unsigned* cs_cnt  = (unsigned*)alloc((size_t)(NN + 1) * 4);
  unsigned* cs_fill = (unsigned*)alloc((size_t)(NN + 1) * 4);
  unsigned* grp_cnt = (unsigned*)alloc((size_t)(NN + 1) * 4);
  size_t zero_bytes = woff;
  // written-before-read region
  int* cluster      = (int*)alloc((size_t)NN * 4);
  int* nlist        = (int*)alloc((size_t)NN * 4);
  unsigned* node_off= (unsigned*)alloc((size_t)(NN + 2) * 4);
  unsigned* cs_off  = (unsigned*)alloc((size_t)(NN + 2) * 4);
  unsigned* grp_base= (unsigned*)alloc((size_t)(NN + 2) * 4);
  unsigned* bsum    = (unsigned*)alloc(4096 * 4);
  unsigned* hdr     = (unsigned*)alloc(256);
  ull* keys         = (ull*)alloc((size_t)EE * 8);

  int* nb_small = (int*)cnt;    // dead after node_off scan
  int* nb_big   = (int*)rank;   // dead after node_cnt_k

  hipMemsetAsync(d_ws, 0, zero_bytes, stream);

  init_hdr_k<<<1, 64, 0, stream>>>(hdr);
  minmax_k<<<128, 256, 0, stream>>>(pos, hdr);
  dims_k<<<1, 64, 0, stream>>>(hdr);
  raw_k<<<(NN + 255) / 256, 256, 0, stream>>>(pos, batch, hdr, cluster, rank);

  auto scan = [&](unsigned* in_, unsigned* out_, int ntot, unsigned* total_out) {
    int nb = (ntot + 1023) / 1024;
    scan_part<<<nb, 256, 0, stream>>>(in_, out_, bsum, ntot, nullptr);
    scan_part<<<1, 256, 0, stream>>>(bsum, bsum, nullptr, nb, total_out);
    scan_add<<<nb, 256, 0, stream>>>(out_, bsum, ntot);
  };
  scan(rank, rank, RAWCAP, hdr + 8);  // rank[raw] = cluster id; total -> n_clusters

  node_cnt_k<<<(NN + 255) / 256, 256, 0, stream>>>(rank, cluster, cnt);
  scan(cnt, node_off, NN + 1, nullptr);
  node_scatter_k<<<(NN + 255) / 256, 256, 0, stream>>>(cluster, node_off, node_fill, nlist);
  cluster_reduce_k<<<2048, 256, 0, stream>>>(x, pos, batch, nlist, node_off, hdr,
                                             out + OX, out + OP, out + OB);
  node_tail_k<<<2048, 256, 0, stream>>>(hdr, out + OX, out + OP, out + OB);

  edge_cnt_k<<<(EE + 255) / 256, 256, 0, stream>>>(ei, cluster, cs_cnt);
  scan(cs_cnt, cs_off, NN + 1, nullptr);
  edge_scatter_k<<<1024, 256, 0, stream>>>(ei, cluster, cs_off, cs_fill, keys);

  compact_k<<<(NN + 255) / 256, 256, 0, stream>>>(cs_off, hdr, nb_small, nb_big);
  group_small_k<<<2048, 256, 0, stream>>>(keys, cs_off, nb_small, hdr, grp_cnt);
  sort_big_k<<<256, 256, 0, stream>>>(keys, cs_off, nb_big, hdr, grp_cnt);
  scan(grp_cnt, grp_base, NN + 1, nullptr);
  emit_small_k<<<4096, 256, 0, stream>>>(keys, cs_off, nb_small, hdr, grp_base, ea,
                                         out + OE, out + OE + EE, out + OA);
  emit_big_k<<<256, 256, 0, stream>>>(keys, cs_off, nb_big, hdr, grp_base, ea,
                                      out + OE, out + OE + EE, out + OA);
  tail_fill_k<<<512, 256, 0, stream>>>(grp_base, out + OE, out + OE + EE, out + OA);
}

// Round 7
// 622.317 us; speedup vs baseline: 1.3421x; 1.3421x over previous
//
#include <hip/hip_runtime.h>

#define NN 300000
#define FF 64
#define EE 2400000
#define FEA 8
#define RAWCAP 131072   // >= 8*129*97 = 100104 guaranteed by IMG_W/H bounds
#define LCAP 2048       // big-bucket bitonic capacity (block path)

typedef unsigned long long ull;

__device__ __forceinline__ unsigned fenc(float f) {
  unsigned b = __float_as_uint(f);
  return (b & 0x80000000u) ? ~b : (b | 0x80000000u);
}
__device__ __forceinline__ float fdec(unsigned e) {
  unsigned b = (e & 0x80000000u) ? (e ^ 0x80000000u) : ~e;
  return __uint_as_float(b);
}

__global__ void init_hdr_k(unsigned* hdr) {
  if (threadIdx.x == 0) {
    hdr[0] = 0xFFFFFFFFu; hdr[1] = 0xFFFFFFFFu;  // min enc
    hdr[2] = 0u;          hdr[3] = 0u;           // max enc
    hdr[9] = 0u;          hdr[10] = 0u;          // compact-list counters
  }
}

// 128 blocks; LDS block-reduce, 4 atomics per block
__global__ void minmax_k(const float* __restrict__ pos, unsigned* hdr) {
  __shared__ unsigned red[4][4];
  int t = blockIdx.x * blockDim.x + threadIdx.x;
  float mnx = 1e30f, mny = 1e30f, mxx = -1e30f, mxy = -1e30f;
  for (int i = t; i < NN; i += gridDim.x * blockDim.x) {
    float px = pos[i * 3 + 1], py = pos[i * 3 + 2];
    mnx = fminf(mnx, px); mny = fminf(mny, py);
    mxx = fmaxf(mxx, px); mxy = fmaxf(mxy, py);
  }
  for (int o = 1; o < 64; o <<= 1) {
    mnx = fminf(mnx, __shfl_xor(mnx, o));
    mny = fminf(mny, __shfl_xor(mny, o));
    mxx = fmaxf(mxx, __shfl_xor(mxx, o));
    mxy = fmaxf(mxy, __shfl_xor(mxy, o));
  }
  int wid = threadIdx.x >> 6;
  if ((threadIdx.x & 63) == 0) {
    red[wid][0] = fenc(mnx); red[wid][1] = fenc(mny);
    red[wid][2] = fenc(mxx); red[wid][3] = fenc(mxy);
  }
  __syncthreads();
  if (threadIdx.x == 0) {
    unsigned a0 = red[0][0], a1 = red[0][1], a2 = red[0][2], a3 = red[0][3];
    for (int k = 1; k < 4; k++) {
      a0 = min(a0, red[k][0]); a1 = min(a1, red[k][1]);
      a2 = max(a2, red[k][2]); a3 = max(a3, red[k][3]);
    }
    atomicMin(&hdr[0], a0); atomicMin(&hdr[1], a1);
    atomicMax(&hdr[2], a2); atomicMax(&hdr[3], a3);
  }
}

__global__ void dims_k(unsigned* hdr) {
  if (threadIdx.x == 0 && blockIdx.x == 0) {
    float mnx = fdec(hdr[0]), mny = fdec(hdr[1]);
    float mxx = fdec(hdr[2]), mxy = fdec(hdr[3]);
    int d0 = (int)(floorf((mxx - mnx) / 5.0f) + 1.0f);
    int d1 = (int)(floorf((mxy - mny) / 5.0f) + 1.0f);
    hdr[4] = (unsigned)d0;
    hdr[5] = (unsigned)d1;
    ((float*)hdr)[6] = mnx;
    ((float*)hdr)[7] = mny;
  }
}

__global__ void raw_k(const float* __restrict__ pos, const int* __restrict__ batch,
                      const unsigned* __restrict__ hdr, int* __restrict__ cluster,
                      unsigned* __restrict__ flags) {
  int i = blockIdx.x * blockDim.x + threadIdx.x;
  if (i >= NN) return;
  float mnx = ((const float*)hdr)[6], mny = ((const float*)hdr)[7];
  int d0 = (int)hdr[4], d1 = (int)hdr[5];
  int c0 = (int)floorf((pos[i * 3 + 1] - mnx) / 5.0f);
  int c1 = (int)floorf((pos[i * 3 + 2] - mny) / 5.0f);
  int raw = batch[i] * (d0 * d1) + c0 * d1 + c1;
  cluster[i] = raw;
  flags[raw] = 1u;
}

// generic exclusive-scan pieces (1024 elems per block)
__global__ void scan_part(const unsigned* __restrict__ in, unsigned* __restrict__ out,
                          unsigned* __restrict__ bsum, int ntot, unsigned* __restrict__ total_out) {
  __shared__ unsigned sc[256];
  int base = blockIdx.x * 1024 + threadIdx.x * 4;
  unsigned v[4]; unsigned s = 0;
#pragma unroll
  for (int k = 0; k < 4; k++) {
    int i = base + k;
    v[k] = (i < ntot) ? in[i] : 0u;
    s += v[k];
  }
  sc[threadIdx.x] = s;
  __syncthreads();
  unsigned xv = s;
  for (int o = 1; o < 256; o <<= 1) {
    unsigned y = (threadIdx.x >= o) ? sc[threadIdx.x - o] : 0u;
    __syncthreads();
    xv += y;
    sc[threadIdx.x] = xv;
    __syncthreads();
  }
  unsigned run = xv - s;
#pragma unroll
  for (int k = 0; k < 4; k++) {
    int i = base + k;
    if (i < ntot) out[i] = run;
    run += v[k];
  }
  if (threadIdx.x == 255) {
    if (bsum) bsum[blockIdx.x] = xv;
    if (total_out && blockIdx.x == 0) *total_out = xv;
  }
}

__global__ void scan_add(unsigned* __restrict__ out, const unsigned* __restrict__ bsum, int ntot) {
  unsigned add = bsum[blockIdx.x];
  int base = blockIdx.x * 1024;
  for (int k = threadIdx.x; k < 1024; k += 256) {
    int i = base + k;
    if (i < ntot) out[i] += add;
  }
}

// map raw->cluster id and count members per cluster
__global__ void node_cnt_k(const unsigned* __restrict__ rank, int* __restrict__ cluster,
                           unsigned* __restrict__ cnt) {
  int i = blockIdx.x * blockDim.x + threadIdx.x;
  if (i >= NN) return;
  int cl = (int)rank[cluster[i]];
  cluster[i] = cl;
  atomicAdd(&cnt[cl], 1u);
}

__global__ void node_scatter_k(const int* __restrict__ cluster,
                               const unsigned* __restrict__ node_off,
                               unsigned* __restrict__ node_fill,
                               int* __restrict__ nlist) {
  int i = blockIdx.x * blockDim.x + threadIdx.x;
  if (i >= NN) return;
  int cl = cluster[i];
  unsigned p = node_off[cl] + atomicAdd(&node_fill[cl], 1u);
  nlist[p] = i;
}

// one wave per cluster: gather member rows, fmax in registers, write once.
__global__ void __launch_bounds__(256)
cluster_reduce_k(const float* __restrict__ x, const float* __restrict__ pos,
                 const int* __restrict__ batch, const int* __restrict__ nlist,
                 const unsigned* __restrict__ node_off, const unsigned* __restrict__ hdr,
                 float* __restrict__ out_x, float* __restrict__ out_pos,
                 float* __restrict__ out_batch) {
  int w = (blockIdx.x * blockDim.x + threadIdx.x) >> 6;
  int nw = (gridDim.x * blockDim.x) >> 6;
  int f = threadIdx.x & 63;
  int ncl = (int)hdr[8];
  for (int c = w; c < ncl; c += nw) {
    unsigned o0 = node_off[c];
    int len = (int)(node_off[c + 1] - o0);
    float mx = -1e38f;
    long long ps = 0;
    for (int m = 0; m < len; m++) {
      int nd = nlist[o0 + m];
      mx = fmaxf(mx, x[(size_t)nd * FF + f]);
      if (f < 3) ps += (long long)llrintf(pos[nd * 3 + f] * 65536.0f);
    }
    out_x[(size_t)c * FF + f] = mx;
    if (f < 3) {
      float v = (float)((double)ps / 65536.0 / (double)len);
      if (f > 0) v = floorf(v / 4.0f);
      out_pos[c * 3 + f] = v;
    }
    if (f == 63) out_batch[c] = (float)batch[nlist[o0]];
  }
}

// rows >= ncl: zeros for x/pos, -1 for batch (exact-range grid-stride)
__global__ void node_tail_k(const unsigned* __restrict__ hdr,
                            float* __restrict__ out_x, float* __restrict__ out_pos,
                            float* __restrict__ out_batch) {
  int ncl = (int)hdr[8];
  int total = (NN - ncl) * FF;
  for (int i = blockIdx.x * blockDim.x + threadIdx.x; i < total;
       i += gridDim.x * blockDim.x) {
    int r = ncl + (i >> 6), f = i & 63;
    out_x[(size_t)r * FF + f] = 0.0f;
    if (f < 3) out_pos[r * 3 + f] = 0.0f;
    if (f == 0) out_batch[r] = -1.0f;
  }
}

__global__ void edge_cnt_k(const int* __restrict__ ei, const int* __restrict__ cluster,
                           unsigned* __restrict__ cs_cnt) {
  int t = blockIdx.x * blockDim.x + threadIdx.x;
  if (t >= EE) return;
  int s = cluster[ei[t]];
  int d = cluster[ei[EE + t]];
  if (s == d) s = NN;
  atomicAdd(&cs_cnt[s], 1u);
}

// simple one-pass scatter (round-5 form, measured 116us; XCD-slicing regressed)
__global__ void edge_scatter_k(const int* __restrict__ ei, const int* __restrict__ cluster,
                               const unsigned* __restrict__ cs_off, unsigned* __restrict__ cs_fill,
                               ull* __restrict__ keys) {
  int t = blockIdx.x * blockDim.x + threadIdx.x;
  if (t >= EE) return;
  int s = cluster[ei[t]];
  int d = cluster[ei[EE + t]];
  if (s == d) return;   // self-loop: never emitted, drop
  unsigned p = cs_off[s] + atomicAdd(&cs_fill[s], 1u);
  keys[p] = ((ull)(unsigned)d << 22) | (unsigned)t;
}

// split non-empty buckets into small (len<=64, wave path) and big (block path);
// wave-aggregated atomics (1/wave, not 1/thread)
__global__ void compact_k(const unsigned* __restrict__ cs_off, unsigned* hdr,
                          int* __restrict__ nb_small, int* __restrict__ nb_big) {
  int b = blockIdx.x * blockDim.x + threadIdx.x;
  int lane = threadIdx.x & 63;
  int len = 0;
  if (b < NN) len = (int)(cs_off[b + 1] - cs_off[b]);
  bool sm = (len > 0) && (len <= 64);
  bool bg = len > 64;
  ull msm = __ballot(sm);
  ull mbg = __ballot(bg);
  unsigned bs = 0, bb = 0;
  if (lane == 0) {
    if (msm) bs = atomicAdd(&hdr[9], (unsigned)__popcll(msm));
    if (mbg) bb = atomicAdd(&hdr[10], (unsigned)__popcll(mbg));
  }
  bs = (unsigned)__shfl((int)bs, 0);
  bb = (unsigned)__shfl((int)bb, 0);
  ull lt = (1ULL << lane) - 1ULL;
  if (sm) nb_small[bs + (unsigned)__popcll(msm & lt)] = b;
  if (bg) nb_big[bb + (unsigned)__popcll(mbg & lt)] = b;
}

// one wave per bucket: head-detect via readlane, store head MASK for emit reuse
__global__ void __launch_bounds__(256)
group_small_k(const ull* __restrict__ keys, const unsigned* __restrict__ cs_off,
              const int* __restrict__ nb_small, const unsigned* __restrict__ hdr,
              unsigned* __restrict__ grp_cnt, ull* __restrict__ headmask) {
  int w = (blockIdx.x * blockDim.x + threadIdx.x) >> 6;
  int nw = (gridDim.x * blockDim.x) >> 6;
  int lane = threadIdx.x & 63;
  int cnt = (int)hdr[9];
  for (int bi = w; bi < cnt; bi += nw) {
    int b = nb_small[bi];
    unsigned o0 = cs_off[b];
    int len = (int)(cs_off[b + 1] - o0);
    unsigned cdv = 0xFFFFFFFFu;
    if (lane < len) cdv = (unsigned)(__builtin_nontemporal_load(&keys[o0 + lane]) >> 22);
    bool head = (lane < len);
    for (int j = 0; j < len; ++j) {
      unsigned cj = (unsigned)__builtin_amdgcn_readlane((int)cdv, j);
      if (cj == cdv && j < lane) head = false;
    }
    ull M = __ballot(head);
    if (lane == 0) {
      grp_cnt[b] = (unsigned)__popcll(M);
      headmask[bi] = M;
    }
  }
}

// one wave per bucket: head mask precomputed; hoisted own-ea load hides gather
// latency under the rank readlane loop; dup-group members merged via reg shfl.
__global__ void __launch_bounds__(256)
emit_small_k(const ull* __restrict__ keys, const unsigned* __restrict__ cs_off,
             const int* __restrict__ nb_small, const unsigned* __restrict__ hdr,
             const unsigned* __restrict__ grp_base, const ull* __restrict__ headmask,
             const float* __restrict__ ea,
             float* __restrict__ out_src, float* __restrict__ out_dst,
             float* __restrict__ out_ea) {
  int w = (blockIdx.x * blockDim.x + threadIdx.x) >> 6;
  int nw = (gridDim.x * blockDim.x) >> 6;
  int lane = threadIdx.x & 63;
  int cnt = (int)hdr[9];
  for (int bi = w; bi < cnt; bi += nw) {
    int b = nb_small[bi];
    unsigned o0 = cs_off[b];
    int len = (int)(cs_off[b + 1] - o0);
    ull M = headmask[bi];
    unsigned cdv = 0xFFFFFFFFu, eidv = 0u;
    if (lane < len) {
      ull key = __builtin_nontemporal_load(&keys[o0 + lane]);
      cdv = (unsigned)(key >> 22);
      eidv = (unsigned)(key & 0x3FFFFFULL);
    }
    float4 v0 = make_float4(0.f, 0.f, 0.f, 0.f), v1 = v0;
    if (lane < len) {
      const float4* p = (const float4*)&ea[(size_t)eidv * FEA];
      v0 = p[0]; v1 = p[1];
    }
    bool head = (M >> lane) & 1ULL;
    bool allsingle = ((int)__popcll(M) == len);
    unsigned r = 0;
    for (int j = 0; j < len; ++j) {
      unsigned cj = (unsigned)__builtin_amdgcn_readlane((int)cdv, j);
      if (((M >> j) & 1ULL) && cj < cdv) r++;
    }
    float4 a0 = v0, a1 = v1;
    if (!allsingle) {
      for (int j = 0; j < len; ++j) {
        unsigned cj = (unsigned)__builtin_amdgcn_readlane((int)cdv, j);
        bool take = (cj == cdv) && (j != lane);
        float t0 = __shfl(v0.x, j), t1 = __shfl(v0.y, j);
        float t2 = __shfl(v0.z, j), t3 = __shfl(v0.w, j);
        float t4 = __shfl(v1.x, j), t5 = __shfl(v1.y, j);
        float t6 = __shfl(v1.z, j), t7 = __shfl(v1.w, j);
        if (take) {
          a0.x += t0; a0.y += t1; a0.z += t2; a0.w += t3;
          a1.x += t4; a1.y += t5; a1.z += t6; a1.w += t7;
        }
      }
    }
    if (head) {
      unsigned row = grp_base[b] + r;
      out_src[row] = (float)b;
      out_dst[row] = (float)cdv;
      float4* o = (float4*)&out_ea[(size_t)row * FEA];
      o[0] = a0; o[1] = a1;
    }
  }
}

__global__ void __launch_bounds__(256)
sort_big_k(ull* __restrict__ keys, const unsigned* __restrict__ cs_off,
           const int* __restrict__ nb_big, const unsigned* __restrict__ hdr,
           unsigned* __restrict__ grp_cnt) {
  __shared__ ull sm[LCAP];
  __shared__ ull rb[256];
  __shared__ int ri[256];
  __shared__ unsigned s4[4];
  int nbig = (int)hdr[10];
  for (int bi = blockIdx.x; bi < nbig; bi += gridDim.x) {
    int b = nb_big[bi];
    unsigned o0 = cs_off[b];
    int len = (int)(cs_off[b + 1] - o0);
    if (len <= LCAP) {
      int np = 1; while (np < len) np <<= 1;
      for (int i = threadIdx.x; i < np; i += 256)
        sm[i] = (i < len) ? keys[o0 + i] : ~0ULL;
      __syncthreads();
      for (int k = 2; k <= np; k <<= 1) {
        for (int j = k >> 1; j > 0; j >>= 1) {
          for (int i = threadIdx.x; i < np; i += 256) {
            int ixj = i ^ j;
            if (ixj > i) {
              ull a = sm[i], c = sm[ixj];
              bool up = ((i & k) == 0);
              if (up ? (a > c) : (a < c)) { sm[i] = c; sm[ixj] = a; }
            }
          }
          __syncthreads();
        }
      }
      unsigned g = 0;
      for (int i = threadIdx.x; i < len; i += 256) {
        ull kk = sm[i];
        keys[o0 + i] = kk;
        unsigned cd = (unsigned)(kk >> 22);
        if (i == 0 || (unsigned)(sm[i - 1] >> 22) != cd) g++;
      }
      for (int o = 32; o > 0; o >>= 1) g += __shfl_down(g, o);
      if ((threadIdx.x & 63) == 0) s4[threadIdx.x >> 6] = g;
      __syncthreads();
      if (threadIdx.x == 0) grp_cnt[b] = s4[0] + s4[1] + s4[2] + s4[3];
      __syncthreads();
    } else {
      for (int p = 0; p < len - 1; p++) {
        ull best = ~0ULL; int bidx = -1;
        for (int i = p + threadIdx.x; i < len; i += 256) {
          ull v = keys[o0 + i];
          if (v < best) { best = v; bidx = i; }
        }
        rb[threadIdx.x] = best; ri[threadIdx.x] = bidx;
        __syncthreads();
        for (int sd = 128; sd > 0; sd >>= 1) {
          if (threadIdx.x < sd && rb[threadIdx.x + sd] < rb[threadIdx.x]) {
            rb[threadIdx.x] = rb[threadIdx.x + sd]; ri[threadIdx.x] = ri[threadIdx.x + sd];
          }
          __syncthreads();
        }
        if (threadIdx.x == 0) {
          int m = ri[0];
          ull tmp = keys[o0 + p];
          keys[o0 + p] = rb[0];
          keys[o0 + m] = tmp;
        }
        __syncthreads();
      }
      unsigned g = 0;
      for (int i = threadIdx.x; i < len; i += 256) {
        unsigned cd = (unsigned)(keys[o0 + i] >> 22);
        if (i == 0 || (unsigned)(keys[o0 + i - 1] >> 22) != cd) g++;
      }
      for (int o = 32; o > 0; o >>= 1) g += __shfl_down(g, o);
      if ((threadIdx.x & 63) == 0) s4[threadIdx.x >> 6] = g;
      __syncthreads();
      if (threadIdx.x == 0) grp_cnt[b] = s4[0] + s4[1] + s4[2] + s4[3];
      __syncthreads();
    }
  }
}

__global__ void __launch_bounds__(256)
emit_big_k(const ull* __restrict__ keys, const unsigned* __restrict__ cs_off,
           const int* __restrict__ nb_big, const unsigned* __restrict__ hdr,
           const unsigned* __restrict__ grp_base, const float* __restrict__ ea,
           float* __restrict__ out_src, float* __restrict__ out_dst,
           float* __restrict__ out_ea) {
  __shared__ unsigned sc[256];
  __shared__ unsigned s_carry;
  int nbig = (int)hdr[10];
  for (int bi = blockIdx.x; bi < nbig; bi += gridDim.x) {
    int b = nb_big[bi];
    unsigned o0 = cs_off[b];
    int len = (int)(cs_off[b + 1] - o0);
    unsigned base = grp_base[b];
    if (threadIdx.x == 0) s_carry = 0;
    __syncthreads();
    for (int c0 = 0; c0 < len; c0 += 256) {
      int i = c0 + threadIdx.x;
      unsigned cd = 0; bool newg = false;
      if (i < len) {
        ull kk = keys[o0 + i];
        cd = (unsigned)(kk >> 22);
        newg = (i == 0) || ((unsigned)(keys[o0 + i - 1] >> 22) != cd);
      }
      unsigned flag = newg ? 1u : 0u;
      sc[threadIdx.x] = flag;
      __syncthreads();
      unsigned xv = flag;
      for (int o = 1; o < 256; o <<= 1) {
        unsigned y = (threadIdx.x >= o) ? sc[threadIdx.x - o] : 0u;
        __syncthreads();
        xv += y;
        sc[threadIdx.x] = xv;
        __syncthreads();
      }
      unsigned carry_old = s_carry;
      if (newg) {
        float a0=0,a1=0,a2=0,a3=0,a4=0,a5=0,a6=0,a7=0;
        int j = i;
        while (j < len) {
          ull k2 = keys[o0 + j];
          if ((unsigned)(k2 >> 22) != cd) break;
          unsigned eid = (unsigned)(k2 & 0x3FFFFFULL);
          const float* p = &ea[(size_t)eid * FEA];
          a0+=p[0];a1+=p[1];a2+=p[2];a3+=p[3];a4+=p[4];a5+=p[5];a6+=p[6];a7+=p[7];
          j++;
        }
        unsigned row = base + carry_old + xv - 1u;
        out_src[row] = (float)b;
        out_dst[row] = (float)cd;
        float* q = &out_ea[(size_t)row * FEA];
        q[0]=a0;q[1]=a1;q[2]=a2;q[3]=a3;q[4]=a4;q[5]=a5;q[6]=a6;q[7]=a7;
      }
      __syncthreads();
      if (threadIdx.x == 255) s_carry = carry_old + xv;
      __syncthreads();
    }
  }
}

// rows >= T (total groups) get -1/-1 and zero ea (exact-range grid-stride)
__global__ void tail_fill_k(const unsigned* __restrict__ grp_base,
                            float* __restrict__ out_src, float* __restrict__ out_dst,
                            float* __restrict__ out_ea) {
  int T = (int)grp_base[NN];
  for (int t = T + blockIdx.x * blockDim.x + threadIdx.x; t < EE;
       t += gridDim.x * blockDim.x) {
    out_src[t] = -1.0f;
    out_dst[t] = -1.0f;
    float4 z = make_float4(0.f, 0.f, 0.f, 0.f);
    float4* o = (float4*)&out_ea[(size_t)t * FEA];
    o[0] = z; o[1] = z;
  }
}

extern "C" void kernel_launch(void* const* d_in, const int* in_sizes, int n_in,
                              void* d_out, int out_size, void* d_ws, size_t ws_size,
                              hipStream_t stream) {
  const float* x   = (const float*)d_in[0];
  const float* pos = (const float*)d_in[1];
  const int* batch = (const int*)d_in[2];
  const int* ei    = (const int*)d_in[3];
  const float* ea  = (const float*)d_in[4];
  float* out = (float*)d_out;

  const size_t OX = 0;
  const size_t OP = (size_t)NN * FF;
  const size_t OB = OP + (size_t)NN * 3;
  const size_t OE = OB + (size_t)NN;
  const size_t OA = OE + (size_t)2 * EE;

  char* w = (char*)d_ws;
  size_t woff = 0;
  auto alloc = [&](size_t bytes) -> void* {
    void* p = w + woff;
    woff += (bytes + 255) & ~(size_t)255;
    return p;
  };
  // zeroed region (one memset)
  unsigned* rank    = (unsigned*)alloc((size_t)RAWCAP * 4);     // reuse: nb_big
  unsigned* cnt     = (unsigned*)alloc((size_t)(NN + 1) * 4);   // reuse: nb_small
  unsigned* node_fill = (unsigned*)alloc((size_t)NN * 4);
  unsigned* cs_cnt  = (unsigned*)alloc((size_t)(NN + 1) * 4);
  unsigned* cs_fill = (unsigned*)alloc((size_t)(NN + 1) * 4);
  unsigned* grp_cnt = (unsigned*)alloc((size_t)(NN + 1) * 4);
  size_t zero_bytes = woff;
  // written-before-read region
  int* cluster      = (int*)alloc((size_t)NN * 4);
  int* nlist        = (int*)alloc((size_t)NN * 4);
  unsigned* node_off= (unsigned*)alloc((size_t)(NN + 2) * 4);
  unsigned* cs_off  = (unsigned*)alloc((size_t)(NN + 2) * 4);
  unsigned* grp_base= (unsigned*)alloc((size_t)(NN + 2) * 4);
  unsigned* bsum    = (unsigned*)alloc(4096 * 4);
  unsigned* hdr     = (unsigned*)alloc(256);
  ull* headmask     = (ull*)alloc((size_t)NN * 8);
  ull* keys         = (ull*)alloc((size_t)EE * 8);

  int* nb_small = (int*)cnt;    // dead after node_off scan
  int* nb_big   = (int*)rank;   // dead after node_cnt_k

  hipMemsetAsync(d_ws, 0, zero_bytes, stream);

  init_hdr_k<<<1, 64, 0, stream>>>(hdr);
  minmax_k<<<128, 256, 0, stream>>>(pos, hdr);
  dims_k<<<1, 64, 0, stream>>>(hdr);
  raw_k<<<(NN + 255) / 256, 256, 0, stream>>>(pos, batch, hdr, cluster, rank);

  auto scan = [&](unsigned* in_, unsigned* out_, int ntot, unsigned* total_out) {
    int nb = (ntot + 1023) / 1024;
    scan_part<<<nb, 256, 0, stream>>>(in_, out_, bsum, ntot, nullptr);
    scan_part<<<1, 256, 0, stream>>>(bsum, bsum, nullptr, nb, total_out);
    scan_add<<<nb, 256, 0, stream>>>(out_, bsum, ntot);
  };
  scan(rank, rank, RAWCAP, hdr + 8);  // rank[raw] = cluster id; total -> n_clusters

  node_cnt_k<<<(NN + 255) / 256, 256, 0, stream>>>(rank, cluster, cnt);
  scan(cnt, node_off, NN + 1, nullptr);
  node_scatter_k<<<(NN + 255) / 256, 256, 0, stream>>>(cluster, node_off, node_fill, nlist);
  cluster_reduce_k<<<2048, 256, 0, stream>>>(x, pos, batch, nlist, node_off, hdr,
                                             out + OX, out + OP, out + OB);
  node_tail_k<<<2048, 256, 0, stream>>>(hdr, out + OX, out + OP, out + OB);

  edge_cnt_k<<<(EE + 255) / 256, 256, 0, stream>>>(ei, cluster, cs_cnt);
  scan(cs_cnt, cs_off, NN + 1, nullptr);
  edge_scatter_k<<<(EE + 255) / 256, 256, 0, stream>>>(ei, cluster, cs_off, cs_fill, keys);

  compact_k<<<(NN + 255) / 256, 256, 0, stream>>>(cs_off, hdr, nb_small, nb_big);
  group_small_k<<<2048, 256, 0, stream>>>(keys, cs_off, nb_small, hdr, grp_cnt, headmask);
  sort_big_k<<<256, 256, 0, stream>>>(keys, cs_off, nb_big, hdr, grp_cnt);
  scan(grp_cnt, grp_base, NN + 1, nullptr);
  emit_small_k<<<4096, 256, 0, stream>>>(keys, cs_off, nb_small, hdr, grp_base, headmask, ea,
                                         out + OE, out + OE + EE, out + OA);
  emit_big_k<<<256, 256, 0, stream>>>(keys, cs_off, nb_big, hdr, grp_base, ea,
                                      out + OE, out + OE + EE, out + OA);
  tail_fill_k<<<512, 256, 0, stream>>>(grp_base, out + OE, out + OE + EE, out + OA);
}